// Round 6
// baseline (333.045 us; speedup 1.0000x reference)
//
#include <hip/hip_runtime.h>
#include <hip/hip_bf16.h>

#define N 8192
#define DIN 128
#define DHID 256
#define DOUT 64
#define LDP 72   // outmm staging LDS row stride (ushorts)
#define VP 136   // V-epilogue LDS row stride (ushorts)

typedef __attribute__((ext_vector_type(8))) short short8;
typedef __attribute__((ext_vector_type(8))) unsigned short u16x8;
typedef __attribute__((ext_vector_type(4))) float f32x4;
typedef __attribute__((ext_vector_type(4))) unsigned short u16x4;

typedef __attribute__((address_space(1))) const unsigned int GlbU32;
typedef __attribute__((address_space(3))) unsigned int LdsU32;

__device__ inline void gload16(const void* g, void* l) {
  __builtin_amdgcn_global_load_lds((GlbU32*)g, (LdsU32*)l, 16, 0, 0);
}

// lgkmcnt-only barrier: LDS ordering without draining vmcnt (stores/prefetch float)
#define LGKM_BAR()                                            \
  do {                                                        \
    asm volatile("s_waitcnt lgkmcnt(0)" ::: "memory");        \
    __builtin_amdgcn_sched_barrier(0);                        \
    __builtin_amdgcn_s_barrier();                             \
    __builtin_amdgcn_sched_barrier(0);                        \
  } while (0)

__device__ inline unsigned short f2bf(float x) {
  unsigned u = __float_as_uint(x);
  u += 0x7FFF + ((u >> 16) & 1);   // RNE
  return (unsigned short)(u >> 16);
}
__device__ inline float bf2f(unsigned short u) {
  return __uint_as_float(((unsigned)u) << 16);
}
__device__ inline float sig_clip(float x) {
  float s = 1.0f / (1.0f + __expf(-x));
  return fmaxf(s, 0.1f);
}

// ---------------- K0: pack (A>0) into interleaved bitmask, 8 MB ----------------
__global__ __launch_bounds__(256) void maskpack(const float* __restrict__ A,
                                                unsigned long long* __restrict__ Mb) {
  size_t i = (size_t)blockIdx.x * 256 + threadIdx.x;
  size_t step = (size_t)gridDim.x * 256;
  int l = threadIdx.x & 63;
  for (; i < (size_t)N * N / 4; i += step) {
    f32x4 a = *(const f32x4*)&A[i * 4];
    unsigned long long b0 = __ballot(a[0] > 0.f);
    unsigned long long b1 = __ballot(a[1] > 0.f);
    unsigned long long b2 = __ballot(a[2] > 0.f);
    unsigned long long b3 = __ballot(a[3] > 0.f);
    size_t g = (i - l) >> 6;
    if (l < 4) {
      unsigned long long bb = (l == 0) ? b0 : (l == 1) ? b1 : (l == 2) ? b2 : b3;
      Mb[g * 4 + l] = bb;
    }
  }
}

// ---------------- K1: BatchNorm statistics ----------------
__global__ void bn_stats(const float* __restrict__ H, const float* __restrict__ bnw,
                         const float* __restrict__ bnb, float* __restrict__ scale,
                         float* __restrict__ shift) {
  int f = blockIdx.x;
  int t = threadIdx.x;
  float s = 0.f, sq = 0.f;
  for (int r = t; r < N; r += 256) {
    float v = H[(size_t)r * DIN + f];
    s += v; sq += v * v;
  }
  __shared__ float ss[256], s2[256];
  ss[t] = s; s2[t] = sq;
  __syncthreads();
  for (int o = 128; o > 0; o >>= 1) {
    if (t < o) { ss[t] += ss[t + o]; s2[t] += s2[t + o]; }
    __syncthreads();
  }
  if (t == 0) {
    float mean = ss[0] * (1.0f / N);
    float var = s2[0] * (1.0f / N) - mean * mean;
    float sc = rsqrtf(var + 1e-5f) * bnw[f];
    scale[f] = sc;
    shift[f] = bnb[f] - mean * sc;
  }
}

// ---------------- K2: Hn -> Hx bf16 [N,256], M2T bf16 [64][N] ----------------
__global__ __launch_bounds__(256) void proj(const float* __restrict__ H,
                     const float* __restrict__ scale, const float* __restrict__ shift,
                     const float* __restrict__ Wt, const float* __restrict__ bt,
                     const float* __restrict__ Wo, const float* __restrict__ bo,
                     unsigned short* __restrict__ Hx, unsigned short* __restrict__ M2T) {
  __shared__ float hn[8][DIN];
  int i0 = blockIdx.x * 8;
  int t = threadIdx.x;
  #pragma unroll
  for (int rep = 0; rep < 4; ++rep) {
    int idx = rep * 256 + t;
    int r = idx >> 7, c = idx & 127;
    float h = H[(size_t)(i0 + r) * DIN + c];
    hn[r][c] = fmaf(h, scale[c], shift[c]);
  }
  __syncthreads();
  {
    int c = t;  // 0..255
    float acc[8];
    float b = bt[c];
    #pragma unroll
    for (int r = 0; r < 8; ++r) acc[r] = b;
    for (int k = 0; k < DIN; ++k) {
      float w = Wt[k * DHID + c];
      #pragma unroll
      for (int r = 0; r < 8; ++r) acc[r] = fmaf(hn[r][k], w, acc[r]);
    }
    #pragma unroll
    for (int r = 0; r < 8; ++r) Hx[(size_t)(i0 + r) * DHID + c] = f2bf(acc[r]);
  }
  if (t < DOUT) {
    int c = t;
    float acc[8];
    float b = bo[c];
    #pragma unroll
    for (int r = 0; r < 8; ++r) acc[r] = b;
    for (int k = 0; k < DIN; ++k) {
      float w = Wo[k * DOUT + c];
      #pragma unroll
      for (int r = 0; r < 8; ++r) acc[r] = fmaf(hn[r][k], w, acc[r]);
    }
    u16x8 v;
    #pragma unroll
    for (int r = 0; r < 8; ++r) v[r] = f2bf(acc[r]);
    *(u16x8*)&M2T[(size_t)c * N + i0] = v;
  }
}

// ---------------- K3: v = clip(sig(Hx Hx^T))*mask + I  (m97-structure K-loop) ----------------
template <int BF16V>
__global__ __launch_bounds__(256) void smat(const unsigned short* __restrict__ Hx,
                     const unsigned long long* __restrict__ Mb,
                     float* __restrict__ rowsum,
                     void* __restrict__ Vout) {
  __shared__ unsigned short lsh[17408];     // staging: la[0..8191], lb[8192..16383]; V tile: [128][VP]
  __shared__ unsigned mbt32[128][4];
  unsigned short* la = lsh;
  unsigned short* lb = lsh + 8192;
  int jt = blockIdx.x, it = blockIdx.y;
  int i0 = it * 128, j0 = jt * 128;
  int t = threadIdx.x;
  int w = t >> 6, l = t & 63;
  int lr = l & 15, lg = l >> 4;

  // mask bits for this tile: 128 rows x 32 used bits per word e=0..3
  if (t < 128) {
    const unsigned long long* src = &Mb[(size_t)(i0 + t) * (N / 64) + (j0 >> 8) * 4];
    int sh = (j0 & 128) ? 32 : 0;
    #pragma unroll
    for (int e = 0; e < 4; ++e)
      mbt32[t][e] = (unsigned)(src[e] >> sh);
  }

  f32x4 acc[2][8];
  f32x4 zero = {0.f, 0.f, 0.f, 0.f};
  #pragma unroll
  for (int m = 0; m < 2; ++m)
    #pragma unroll
    for (int n = 0; n < 8; ++n) acc[m][n] = zero;

  const int srow = l >> 3;                 // row within 8-row chunk
  const int scol = ((l & 7) ^ srow) * 8;   // pre-swizzled global col group
  const int fswz = (lr & 7) * 8;           // fragment-read XOR (row&7)*8

  for (int c4 = 0; c4 < 4; ++c4) {
    int k0 = c4 * 64;
    __syncthreads();                        // previous tile fully consumed
    #pragma unroll
    for (int rp = 0; rp < 4; ++rp) {
      int chunk = rp * 4 + w;               // 0..15, wave-uniform LDS base
      int row = chunk * 8 + srow;
      gload16(&Hx[(size_t)(i0 + row) * DHID + k0 + scol], &la[chunk * 512]);
      gload16(&Hx[(size_t)(j0 + row) * DHID + k0 + scol], &lb[chunk * 512]);
    }
    __syncthreads();                        // drains staging
    #pragma unroll
    for (int kk = 0; kk < 2; ++kk) {
      int c = (kk * 32 + lg * 8) ^ fswz;
      short8 af[2], bf[8];
      #pragma unroll
      for (int m = 0; m < 2; ++m)
        af[m] = *(const short8*)&la[(w * 32 + m * 16 + lr) * 64 + c];
      #pragma unroll
      for (int n = 0; n < 8; ++n)
        bf[n] = *(const short8*)&lb[(n * 16 + lr) * 64 + c];
      #pragma unroll
      for (int m = 0; m < 2; ++m)
        #pragma unroll
        for (int n = 0; n < 8; ++n)
          acc[m][n] = __builtin_amdgcn_mfma_f32_16x16x32_bf16(af[m], bf[n], acc[m][n], 0, 0, 0);
    }
  }

  if (BF16V) __syncthreads();  // about to overwrite lsh with the V tile

  #pragma unroll
  for (int m = 0; m < 2; ++m) {
    #pragma unroll
    for (int r = 0; r < 4; ++r) {
      int rl = w * 32 + m * 16 + lg * 4 + r;
      int gi = i0 + rl;
      unsigned mw = mbt32[rl][lr & 3];
      float part = 0.f;
      #pragma unroll
      for (int n = 0; n < 8; ++n) {
        int gj = j0 + n * 16 + lr;
        float ms = ((mw >> (n * 4 + (lr >> 2))) & 1u) ? 1.f : 0.f;
        float v = sig_clip(acc[m][n][r]) * ms + (gi == gj ? 1.f : 0.f);
        part += v;
        if (BF16V)
          lsh[rl * VP + n * 16 + lr] = f2bf(v);
        else
          ((float*)Vout)[(size_t)gi * N + gj] = v;
      }
      part += __shfl_xor(part, 1);
      part += __shfl_xor(part, 2);
      part += __shfl_xor(part, 4);
      part += __shfl_xor(part, 8);
      if (lr == 0) atomicAdd(&rowsum[gi], part);
    }
  }

  if (BF16V) {
    __syncthreads();
    #pragma unroll
    for (int pass = 0; pass < 8; ++pass) {
      int row = pass * 16 + (t >> 4);
      int cc = (t & 15) * 8;
      u16x8 vv = *(const u16x8*)&lsh[row * VP + cc];
      *(u16x8*)&((unsigned short*)Vout)[(size_t)(i0 + row) * N + j0 + cc] = vv;
    }
  }
}

// ---------------- K3b: d = rsqrt(rowsum), in place ----------------
__global__ void dfin(float* rs) {
  int i = blockIdx.x * 256 + threadIdx.x;
  if (i < N) rs[i] = rsqrtf(rs[i]);
}

// ---------------- K4: fused scale + A_hat write + out = A_hat @ M2 ----------------
// bf16 path: V-prefetch double-buffer (T14), lgkmcnt-only barriers (stores float),
// LDS double-buffer -> 1 barrier/step.
template <int BF16V>
__global__ __launch_bounds__(256) void outmm(const void* __restrict__ Vin,
                      const float* __restrict__ dd,
                      const unsigned short* __restrict__ M2T,
                      float* __restrict__ Ahat, float* __restrict__ out) {
  __shared__ unsigned short la[2][128 * LDP];
  int kc = blockIdx.x;   // 0..15  (j-chunk of 512)
  int it = blockIdx.y;   // 0..63  (i-tile of 128)
  int i0 = it * 128;
  int jbase = kc * 512;
  int t = threadIdx.x;
  int w = t >> 6, l = t & 63;
  int lr = l & 15, lg = l >> 4;

  f32x4 acc[2][4];
  f32x4 zero = {0.f, 0.f, 0.f, 0.f};
  #pragma unroll
  for (int m = 0; m < 2; ++m)
    #pragma unroll
    for (int n = 0; n < 4; ++n) acc[m][n] = zero;

  if (BF16V) {
    const unsigned short* V = (const unsigned short*)Vin;
    const int row8 = t >> 3;      // 0..31
    const int cc8 = (t & 7) * 8;  // 0..56

    float di[4];
    #pragma unroll
    for (int rep = 0; rep < 4; ++rep) di[rep] = dd[i0 + rep * 32 + row8];

    u16x8 u[2][4];
    #pragma unroll
    for (int rep = 0; rep < 4; ++rep)
      u[0][rep] = *(const u16x8*)&V[(size_t)(i0 + rep * 32 + row8) * N + jbase + cc8];

    #pragma unroll
    for (int s = 0; s < 8; ++s) {
      const int cur = s & 1;
      const int j0 = jbase + s * 64;
      // prefetch next step's V into the other reg set
      if (s < 7) {
        #pragma unroll
        for (int rep = 0; rep < 4; ++rep)
          u[cur ^ 1][rep] = *(const u16x8*)&V[(size_t)(i0 + rep * 32 + row8) * N + j0 + 64 + cc8];
      }
      // hoist M2T fragment loads (used after the barrier; latency hides under scale VALU)
      short8 bfr[2][4];
      #pragma unroll
      for (int kk = 0; kk < 2; ++kk)
        #pragma unroll
        for (int n = 0; n < 4; ++n)
          bfr[kk][n] = *(const short8*)&M2T[(size_t)(n * 16 + lr) * N + j0 + kk * 32 + lg * 8];
      // scale + Ahat store + ds_write la[cur]
      f32x4 dj0 = *(const f32x4*)&dd[j0 + cc8];
      f32x4 dj1 = *(const f32x4*)&dd[j0 + cc8 + 4];
      #pragma unroll
      for (int rep = 0; rep < 4; ++rep) {
        int row = rep * 32 + row8;
        size_t idx = (size_t)(i0 + row) * N + j0 + cc8;
        f32x4 s0, s1;
        s0[0] = bf2f(u[cur][rep][0]) * di[rep] * dj0[0];
        s0[1] = bf2f(u[cur][rep][1]) * di[rep] * dj0[1];
        s0[2] = bf2f(u[cur][rep][2]) * di[rep] * dj0[2];
        s0[3] = bf2f(u[cur][rep][3]) * di[rep] * dj0[3];
        s1[0] = bf2f(u[cur][rep][4]) * di[rep] * dj1[0];
        s1[1] = bf2f(u[cur][rep][5]) * di[rep] * dj1[1];
        s1[2] = bf2f(u[cur][rep][6]) * di[rep] * dj1[2];
        s1[3] = bf2f(u[cur][rep][7]) * di[rep] * dj1[3];
        *(f32x4*)&Ahat[idx] = s0;
        *(f32x4*)&Ahat[idx + 4] = s1;
        u16x8 b;
        b[0] = f2bf(s0[0]); b[1] = f2bf(s0[1]); b[2] = f2bf(s0[2]); b[3] = f2bf(s0[3]);
        b[4] = f2bf(s1[0]); b[5] = f2bf(s1[1]); b[6] = f2bf(s1[2]); b[7] = f2bf(s1[3]);
        *(u16x8*)&la[cur][row * LDP + cc8] = b;
      }
      LGKM_BAR();   // ds_writes visible; Ahat stores & prefetch loads keep flying
      #pragma unroll
      for (int kk = 0; kk < 2; ++kk) {
        short8 af[2];
        #pragma unroll
        for (int m = 0; m < 2; ++m)
          af[m] = *(const short8*)&la[cur][(w * 32 + m * 16 + lr) * LDP + kk * 32 + lg * 8];
        #pragma unroll
        for (int m = 0; m < 2; ++m)
          #pragma unroll
          for (int n = 0; n < 4; ++n)
            acc[m][n] = __builtin_amdgcn_mfma_f32_16x16x32_bf16(af[m], bfr[kk][n], acc[m][n], 0, 0, 0);
      }
      // no second barrier: next step ds_writes the OTHER LDS half; each wave's own
      // ds_reads complete before its next LGKM_BAR, which gates the half's reuse at s+2.
    }
  } else {
    for (int s = 0; s < 8; ++s) {
      int j0 = jbase + s * 64;
      __syncthreads();
      #pragma unroll
      for (int rep = 0; rep < 8; ++rep) {
        int row = rep * 16 + (t >> 4);
        int cc = (t & 15) * 4;
        size_t idx = (size_t)(i0 + row) * N + j0 + cc;
        f32x4 v = *(const f32x4*)&((const float*)Vin)[idx];
        float dii = dd[i0 + row];
        f32x4 dj = *(const f32x4*)&dd[j0 + cc];
        f32x4 sv;
        sv[0] = v[0] * dii * dj[0]; sv[1] = v[1] * dii * dj[1];
        sv[2] = v[2] * dii * dj[2]; sv[3] = v[3] * dii * dj[3];
        *(f32x4*)&Ahat[idx] = sv;
        u16x4 b;
        b[0] = f2bf(sv[0]); b[1] = f2bf(sv[1]); b[2] = f2bf(sv[2]); b[3] = f2bf(sv[3]);
        *(u16x4*)&la[0][row * LDP + cc] = b;
      }
      __syncthreads();
      #pragma unroll
      for (int kk = 0; kk < 2; ++kk) {
        short8 af[2], bfr[4];
        #pragma unroll
        for (int m = 0; m < 2; ++m)
          af[m] = *(const short8*)&la[0][(w * 32 + m * 16 + lr) * LDP + kk * 32 + lg * 8];
        #pragma unroll
        for (int n = 0; n < 4; ++n)
          bfr[n] = *(const short8*)&M2T[(size_t)(n * 16 + lr) * N + j0 + kk * 32 + lg * 8];
        #pragma unroll
        for (int m = 0; m < 2; ++m)
          #pragma unroll
          for (int n = 0; n < 4; ++n)
            acc[m][n] = __builtin_amdgcn_mfma_f32_16x16x32_bf16(af[m], bfr[n], acc[m][n], 0, 0, 0);
      }
    }
  }

  #pragma unroll
  for (int m = 0; m < 2; ++m)
    #pragma unroll
    for (int n = 0; n < 4; ++n)
      #pragma unroll
      for (int r = 0; r < 4; ++r) {
        int gi = i0 + w * 32 + m * 16 + lg * 4 + r;
        int gc = n * 16 + lr;
        atomicAdd(&out[(size_t)gi * DOUT + gc], acc[m][n][r]);
      }
}

// ---------------- K5: LeakyReLU on out ----------------
__global__ void leaky(float* out) {
  int i = blockIdx.x * 256 + threadIdx.x;
  if (i < N * DOUT) {
    float x = out[i];
    out[i] = x >= 0.f ? x : 0.01f * x;
  }
}

extern "C" void kernel_launch(void* const* d_in, const int* in_sizes, int n_in,
                              void* d_out, int out_size, void* d_ws, size_t ws_size,
                              hipStream_t stream) {
  const float* H   = (const float*)d_in[0];
  const float* A   = (const float*)d_in[1];
  const float* bnw = (const float*)d_in[2];
  const float* bnb = (const float*)d_in[3];
  const float* Wt  = (const float*)d_in[4];
  const float* bt  = (const float*)d_in[5];
  const float* Wo  = (const float*)d_in[6];
  const float* bo  = (const float*)d_in[7];
  float* out = (float*)d_out;
  float* Ahat = out + (size_t)N * DOUT;

  char* ws = (char*)d_ws;
  float* scale  = (float*)(ws + 0);
  float* shift  = (float*)(ws + 512);
  float* rowsum = (float*)(ws + 4096);                    // 32 KB, becomes d after dfin
  unsigned short* M2T = (unsigned short*)(ws + 65536);    // 1 MB slot [64][N]
  unsigned short* Hx  = (unsigned short*)(ws + 2097152);  // 4 MB slot
  unsigned long long* Mb = (unsigned long long*)(ws + (size_t)(6u << 20));  // 8 MB bitmask
  unsigned short* Vbf = (unsigned short*)(ws + (size_t)(14u << 20));        // 134 MB slot

  const size_t need_bf16 = ((size_t)14 << 20) + (size_t)N * N * 2;
  const bool big = ws_size >= need_bf16;

  hipMemsetAsync(rowsum, 0, N * sizeof(float), stream);
  hipMemsetAsync(out, 0, (size_t)N * DOUT * sizeof(float), stream);

  maskpack<<<4096, 256, 0, stream>>>(A, Mb);
  bn_stats<<<DIN, 256, 0, stream>>>(H, bnw, bnb, scale, shift);
  proj<<<N / 8, 256, 0, stream>>>(H, scale, shift, Wt, bt, Wo, bo, Hx, M2T);
  if (big) {
    smat<1><<<dim3(64, 64), 256, 0, stream>>>(Hx, Mb, rowsum, (void*)Vbf);
    dfin<<<N / 256, 256, 0, stream>>>(rowsum);
    outmm<1><<<dim3(16, 64), 256, 0, stream>>>((const void*)Vbf, rowsum, M2T, Ahat, out);
  } else {
    smat<0><<<dim3(64, 64), 256, 0, stream>>>(Hx, Mb, rowsum, (void*)Ahat);
    dfin<<<N / 256, 256, 0, stream>>>(rowsum);
    outmm<0><<<dim3(16, 64), 256, 0, stream>>>((const void*)Ahat, rowsum, M2T, Ahat, out);
  }
  leaky<<<(N * DOUT + 255) / 256, 256, 0, stream>>>(out);
}

// Round 7
// 318.763 us; speedup vs baseline: 1.0448x; 1.0448x over previous
//
#include <hip/hip_runtime.h>
#include <hip/hip_bf16.h>

#define N 8192
#define DIN 128
#define DHID 256
#define DOUT 64
#define LDP 72   // outmm staging LDS row stride (ushorts)
#define VP 136   // V-epilogue LDS row stride (ushorts)

typedef __attribute__((ext_vector_type(8))) short short8;
typedef __attribute__((ext_vector_type(8))) unsigned short u16x8;
typedef __attribute__((ext_vector_type(4))) float f32x4;
typedef __attribute__((ext_vector_type(4))) unsigned short u16x4;

typedef __attribute__((address_space(1))) const unsigned int GlbU32;
typedef __attribute__((address_space(3))) unsigned int LdsU32;

__device__ inline void gload16(const void* g, void* l) {
  __builtin_amdgcn_global_load_lds((GlbU32*)g, (LdsU32*)l, 16, 0, 0);
}

// lgkmcnt-only barrier: LDS ordering without draining vmcnt
#define LGKM_BAR()                                            \
  do {                                                        \
    asm volatile("s_waitcnt lgkmcnt(0)" ::: "memory");        \
    __builtin_amdgcn_sched_barrier(0);                        \
    __builtin_amdgcn_s_barrier();                             \
    __builtin_amdgcn_sched_barrier(0);                        \
  } while (0)

__device__ inline unsigned short f2bf(float x) {
  unsigned u = __float_as_uint(x);
  u += 0x7FFF + ((u >> 16) & 1);   // RNE
  return (unsigned short)(u >> 16);
}
__device__ inline float bf2f(unsigned short u) {
  return __uint_as_float(((unsigned)u) << 16);
}
__device__ inline float sig_clip(float x) {
  float s = 1.0f / (1.0f + __expf(-x));
  return fmaxf(s, 0.1f);
}

// ---------------- K0: pack (A>0) into interleaved bitmask, 8 MB ----------------
__global__ __launch_bounds__(256) void maskpack(const float* __restrict__ A,
                                                unsigned long long* __restrict__ Mb) {
  size_t i = (size_t)blockIdx.x * 256 + threadIdx.x;
  size_t step = (size_t)gridDim.x * 256;
  int l = threadIdx.x & 63;
  for (; i < (size_t)N * N / 4; i += step) {
    f32x4 a = *(const f32x4*)&A[i * 4];
    unsigned long long b0 = __ballot(a[0] > 0.f);
    unsigned long long b1 = __ballot(a[1] > 0.f);
    unsigned long long b2 = __ballot(a[2] > 0.f);
    unsigned long long b3 = __ballot(a[3] > 0.f);
    size_t g = (i - l) >> 6;
    if (l < 4) {
      unsigned long long bb = (l == 0) ? b0 : (l == 1) ? b1 : (l == 2) ? b2 : b3;
      Mb[g * 4 + l] = bb;
    }
  }
}

// ---------------- K1: BatchNorm statistics ----------------
__global__ void bn_stats(const float* __restrict__ H, const float* __restrict__ bnw,
                         const float* __restrict__ bnb, float* __restrict__ scale,
                         float* __restrict__ shift) {
  int f = blockIdx.x;
  int t = threadIdx.x;
  float s = 0.f, sq = 0.f;
  for (int r = t; r < N; r += 256) {
    float v = H[(size_t)r * DIN + f];
    s += v; sq += v * v;
  }
  __shared__ float ss[256], s2[256];
  ss[t] = s; s2[t] = sq;
  __syncthreads();
  for (int o = 128; o > 0; o >>= 1) {
    if (t < o) { ss[t] += ss[t + o]; s2[t] += s2[t + o]; }
    __syncthreads();
  }
  if (t == 0) {
    float mean = ss[0] * (1.0f / N);
    float var = s2[0] * (1.0f / N) - mean * mean;
    float sc = rsqrtf(var + 1e-5f) * bnw[f];
    scale[f] = sc;
    shift[f] = bnb[f] - mean * sc;
  }
}

// ---------------- K2: Hn -> Hx bf16 [N,256], M2T bf16 [64][N] ----------------
__global__ __launch_bounds__(256) void proj(const float* __restrict__ H,
                     const float* __restrict__ scale, const float* __restrict__ shift,
                     const float* __restrict__ Wt, const float* __restrict__ bt,
                     const float* __restrict__ Wo, const float* __restrict__ bo,
                     unsigned short* __restrict__ Hx, unsigned short* __restrict__ M2T) {
  __shared__ float hn[8][DIN];
  int i0 = blockIdx.x * 8;
  int t = threadIdx.x;
  #pragma unroll
  for (int rep = 0; rep < 4; ++rep) {
    int idx = rep * 256 + t;
    int r = idx >> 7, c = idx & 127;
    float h = H[(size_t)(i0 + r) * DIN + c];
    hn[r][c] = fmaf(h, scale[c], shift[c]);
  }
  __syncthreads();
  {
    int c = t;  // 0..255
    float acc[8];
    float b = bt[c];
    #pragma unroll
    for (int r = 0; r < 8; ++r) acc[r] = b;
    for (int k = 0; k < DIN; ++k) {
      float w = Wt[k * DHID + c];
      #pragma unroll
      for (int r = 0; r < 8; ++r) acc[r] = fmaf(hn[r][k], w, acc[r]);
    }
    #pragma unroll
    for (int r = 0; r < 8; ++r) Hx[(size_t)(i0 + r) * DHID + c] = f2bf(acc[r]);
  }
  if (t < DOUT) {
    int c = t;
    float acc[8];
    float b = bo[c];
    #pragma unroll
    for (int r = 0; r < 8; ++r) acc[r] = b;
    for (int k = 0; k < DIN; ++k) {
      float w = Wo[k * DOUT + c];
      #pragma unroll
      for (int r = 0; r < 8; ++r) acc[r] = fmaf(hn[r][k], w, acc[r]);
    }
    u16x8 v;
    #pragma unroll
    for (int r = 0; r < 8; ++r) v[r] = f2bf(acc[r]);
    *(u16x8*)&M2T[(size_t)c * N + i0] = v;
  }
}

// ---------------- K3: v = clip(sig(Hx Hx^T))*mask + I, SYMMETRIC (it<=jt only) ----------------
// Off-diagonal blocks emit both the (i,j) tile and the transposed (j,i) tile
// (different masks), plus row sums for i-rows and column sums for j-rows.
template <int BF16V>
__global__ __launch_bounds__(256) void smat(const unsigned short* __restrict__ Hx,
                     const unsigned long long* __restrict__ Mb,
                     float* __restrict__ rowsum,
                     void* __restrict__ Vout) {
  int jt = blockIdx.x, it = blockIdx.y;
  if (BF16V && jt < it) return;               // symmetric: upper triangle only
  __shared__ unsigned short lsh[17408];       // staging la/lb; later the V tile [128][VP]
  __shared__ unsigned mbt32[128][4];
  __shared__ unsigned mbtT[128][4];
  __shared__ float scs[4][128];
  unsigned short* la = lsh;
  unsigned short* lb = lsh + 8192;
  int i0 = it * 128, j0 = jt * 128;
  int t = threadIdx.x;
  int w = t >> 6, l = t & 63;
  int lr = l & 15, lg = l >> 4;
  const bool offdiag = BF16V && (it != jt);

  // upper mask: rows i0.., cols j0..
  if (t < 128) {
    const unsigned long long* src = &Mb[(size_t)(i0 + t) * (N / 64) + (j0 >> 8) * 4];
    int sh = (j0 & 128) ? 32 : 0;
    #pragma unroll
    for (int e = 0; e < 4; ++e)
      mbt32[t][e] = (unsigned)(src[e] >> sh);
  }
  // transposed mask: rows j0.., cols i0..
  if (offdiag && t < 128) {
    const unsigned long long* srcT = &Mb[(size_t)(j0 + t) * (N / 64) + (i0 >> 8) * 4];
    int shT = (i0 & 128) ? 32 : 0;
    #pragma unroll
    for (int e = 0; e < 4; ++e)
      mbtT[t][e] = (unsigned)(srcT[e] >> shT);
  }

  f32x4 acc[2][8];
  f32x4 zero = {0.f, 0.f, 0.f, 0.f};
  #pragma unroll
  for (int m = 0; m < 2; ++m)
    #pragma unroll
    for (int n = 0; n < 8; ++n) acc[m][n] = zero;

  const int srow = l >> 3;                 // row within 8-row chunk
  const int scol = ((l & 7) ^ srow) * 8;   // pre-swizzled global col group
  const int fswz = (lr & 7) * 8;           // fragment-read XOR (row&7)*8

  for (int c4 = 0; c4 < 4; ++c4) {
    int k0 = c4 * 64;
    __syncthreads();
    #pragma unroll
    for (int rp = 0; rp < 4; ++rp) {
      int chunk = rp * 4 + w;
      int row = chunk * 8 + srow;
      gload16(&Hx[(size_t)(i0 + row) * DHID + k0 + scol], &la[chunk * 512]);
      gload16(&Hx[(size_t)(j0 + row) * DHID + k0 + scol], &lb[chunk * 512]);
    }
    __syncthreads();
    #pragma unroll
    for (int kk = 0; kk < 2; ++kk) {
      int c = (kk * 32 + lg * 8) ^ fswz;
      short8 af[2], bf[8];
      #pragma unroll
      for (int m = 0; m < 2; ++m)
        af[m] = *(const short8*)&la[(w * 32 + m * 16 + lr) * 64 + c];
      #pragma unroll
      for (int n = 0; n < 8; ++n)
        bf[n] = *(const short8*)&lb[(n * 16 + lr) * 64 + c];
      #pragma unroll
      for (int m = 0; m < 2; ++m)
        #pragma unroll
        for (int n = 0; n < 8; ++n)
          acc[m][n] = __builtin_amdgcn_mfma_f32_16x16x32_bf16(af[m], bf[n], acc[m][n], 0, 0, 0);
    }
  }

  if (BF16V) __syncthreads();  // staging fully consumed; lsh becomes the V tile

  // ---- upper tile: v_up = sig*m_up (+I on diag), row sums ----
  #pragma unroll
  for (int m = 0; m < 2; ++m) {
    #pragma unroll
    for (int r = 0; r < 4; ++r) {
      int rl = w * 32 + m * 16 + lg * 4 + r;
      int gi = i0 + rl;
      unsigned mw = mbt32[rl][lr & 3];
      float part = 0.f;
      #pragma unroll
      for (int n = 0; n < 8; ++n) {
        int gj = j0 + n * 16 + lr;
        float ms = ((mw >> (n * 4 + (lr >> 2))) & 1u) ? 1.f : 0.f;
        float v = sig_clip(acc[m][n][r]) * ms + (gi == gj ? 1.f : 0.f);
        part += v;
        if (BF16V)
          lsh[rl * VP + n * 16 + lr] = f2bf(v);
        else
          ((float*)Vout)[(size_t)gi * N + gj] = v;
      }
      part += __shfl_xor(part, 1);
      part += __shfl_xor(part, 2);
      part += __shfl_xor(part, 4);
      part += __shfl_xor(part, 8);
      if (lr == 0) atomicAdd(&rowsum[gi], part);
    }
  }

  if (BF16V) {
    __syncthreads();
    #pragma unroll
    for (int pass = 0; pass < 8; ++pass) {
      int row = pass * 16 + (t >> 4);
      int cc = (t & 15) * 8;
      u16x8 vv = *(const u16x8*)&lsh[row * VP + cc];
      *(u16x8*)&((unsigned short*)Vout)[(size_t)(i0 + row) * N + j0 + cc] = vv;
    }
  }

  // ---- lower (transposed) tile: v_lo = sig*m_lo, column sums -> rowsum[j-rows] ----
  if (offdiag) {
    __syncthreads();   // upper store pass done reading lsh
    float p[8];
    #pragma unroll
    for (int n = 0; n < 8; ++n) p[n] = 0.f;
    #pragma unroll
    for (int m = 0; m < 2; ++m) {
      #pragma unroll
      for (int r = 0; r < 4; ++r) {
        int rl = w * 32 + m * 16 + lg * 4 + r;
        int bitp = w * 8 + m * 4 + lg;
        #pragma unroll
        for (int n = 0; n < 8; ++n) {
          int c = n * 16 + lr;                       // j-row within tile
          float ms = ((mbtT[c][r] >> bitp) & 1u) ? 1.f : 0.f;
          float v = sig_clip(acc[m][n][r]) * ms;
          p[n] += v;
          lsh[c * VP + rl] = f2bf(v);                // transposed position
        }
      }
    }
    // reduce col partials over lg (lanes lg*16+lr)
    #pragma unroll
    for (int n = 0; n < 8; ++n) {
      p[n] += __shfl_xor(p[n], 16);
      p[n] += __shfl_xor(p[n], 32);
    }
    if (lg == 0) {
      #pragma unroll
      for (int n = 0; n < 8; ++n) scs[w][n * 16 + lr] = p[n];
    }
    __syncthreads();
    if (t < 128) {
      float cs = scs[0][t] + scs[1][t] + scs[2][t] + scs[3][t];
      atomicAdd(&rowsum[j0 + t], cs);
    }
    // coalesced store of the transposed tile: rows j0.., cols i0..
    #pragma unroll
    for (int pass = 0; pass < 8; ++pass) {
      int row = pass * 16 + (t >> 4);
      int cc = (t & 15) * 8;
      u16x8 vv = *(const u16x8*)&lsh[row * VP + cc];
      *(u16x8*)&((unsigned short*)Vout)[(size_t)(j0 + row) * N + i0 + cc] = vv;
    }
  }
}

// ---------------- K3b: d = rsqrt(rowsum), in place ----------------
__global__ void dfin(float* rs) {
  int i = blockIdx.x * 256 + threadIdx.x;
  if (i < N) rs[i] = rsqrtf(rs[i]);
}

// ---------------- K4: fused scale + A_hat write + out = A_hat @ M2 ----------------
template <int BF16V>
__global__ __launch_bounds__(256) void outmm(const void* __restrict__ Vin,
                      const float* __restrict__ dd,
                      const unsigned short* __restrict__ M2T,
                      float* __restrict__ Ahat, float* __restrict__ out) {
  __shared__ unsigned short la[2][128 * LDP];
  int kc = blockIdx.x;   // 0..15  (j-chunk of 512)
  int it = blockIdx.y;   // 0..63  (i-tile of 128)
  int i0 = it * 128;
  int jbase = kc * 512;
  int t = threadIdx.x;
  int w = t >> 6, l = t & 63;
  int lr = l & 15, lg = l >> 4;

  f32x4 acc[2][4];
  f32x4 zero = {0.f, 0.f, 0.f, 0.f};
  #pragma unroll
  for (int m = 0; m < 2; ++m)
    #pragma unroll
    for (int n = 0; n < 4; ++n) acc[m][n] = zero;

  if (BF16V) {
    const unsigned short* V = (const unsigned short*)Vin;
    const int row8 = t >> 3;      // 0..31
    const int cc8 = (t & 7) * 8;  // 0..56

    float di[4];
    #pragma unroll
    for (int rep = 0; rep < 4; ++rep) di[rep] = dd[i0 + rep * 32 + row8];

    u16x8 u[2][4];
    #pragma unroll
    for (int rep = 0; rep < 4; ++rep)
      u[0][rep] = *(const u16x8*)&V[(size_t)(i0 + rep * 32 + row8) * N + jbase + cc8];

    #pragma unroll
    for (int s = 0; s < 8; ++s) {
      const int cur = s & 1;
      const int j0 = jbase + s * 64;
      if (s < 7) {
        #pragma unroll
        for (int rep = 0; rep < 4; ++rep)
          u[cur ^ 1][rep] = *(const u16x8*)&V[(size_t)(i0 + rep * 32 + row8) * N + j0 + 64 + cc8];
      }
      short8 bfr[2][4];
      #pragma unroll
      for (int kk = 0; kk < 2; ++kk)
        #pragma unroll
        for (int n = 0; n < 4; ++n)
          bfr[kk][n] = *(const short8*)&M2T[(size_t)(n * 16 + lr) * N + j0 + kk * 32 + lg * 8];
      f32x4 dj0 = *(const f32x4*)&dd[j0 + cc8];
      f32x4 dj1 = *(const f32x4*)&dd[j0 + cc8 + 4];
      #pragma unroll
      for (int rep = 0; rep < 4; ++rep) {
        int row = rep * 32 + row8;
        size_t idx = (size_t)(i0 + row) * N + j0 + cc8;
        f32x4 s0, s1;
        s0[0] = bf2f(u[cur][rep][0]) * di[rep] * dj0[0];
        s0[1] = bf2f(u[cur][rep][1]) * di[rep] * dj0[1];
        s0[2] = bf2f(u[cur][rep][2]) * di[rep] * dj0[2];
        s0[3] = bf2f(u[cur][rep][3]) * di[rep] * dj0[3];
        s1[0] = bf2f(u[cur][rep][4]) * di[rep] * dj1[0];
        s1[1] = bf2f(u[cur][rep][5]) * di[rep] * dj1[1];
        s1[2] = bf2f(u[cur][rep][6]) * di[rep] * dj1[2];
        s1[3] = bf2f(u[cur][rep][7]) * di[rep] * dj1[3];
        *(f32x4*)&Ahat[idx] = s0;
        *(f32x4*)&Ahat[idx + 4] = s1;
        u16x8 b;
        b[0] = f2bf(s0[0]); b[1] = f2bf(s0[1]); b[2] = f2bf(s0[2]); b[3] = f2bf(s0[3]);
        b[4] = f2bf(s1[0]); b[5] = f2bf(s1[1]); b[6] = f2bf(s1[2]); b[7] = f2bf(s1[3]);
        *(u16x8*)&la[cur][row * LDP + cc8] = b;
      }
      LGKM_BAR();
      #pragma unroll
      for (int kk = 0; kk < 2; ++kk) {
        short8 af[2];
        #pragma unroll
        for (int m = 0; m < 2; ++m)
          af[m] = *(const short8*)&la[cur][(w * 32 + m * 16 + lr) * LDP + kk * 32 + lg * 8];
        #pragma unroll
        for (int m = 0; m < 2; ++m)
          #pragma unroll
          for (int n = 0; n < 4; ++n)
            acc[m][n] = __builtin_amdgcn_mfma_f32_16x16x32_bf16(af[m], bfr[kk][n], acc[m][n], 0, 0, 0);
      }
    }
  } else {
    for (int s = 0; s < 8; ++s) {
      int j0 = jbase + s * 64;
      __syncthreads();
      #pragma unroll
      for (int rep = 0; rep < 8; ++rep) {
        int row = rep * 16 + (t >> 4);
        int cc = (t & 15) * 4;
        size_t idx = (size_t)(i0 + row) * N + j0 + cc;
        f32x4 v = *(const f32x4*)&((const float*)Vin)[idx];
        float dii = dd[i0 + row];
        f32x4 dj = *(const f32x4*)&dd[j0 + cc];
        f32x4 sv;
        sv[0] = v[0] * dii * dj[0]; sv[1] = v[1] * dii * dj[1];
        sv[2] = v[2] * dii * dj[2]; sv[3] = v[3] * dii * dj[3];
        *(f32x4*)&Ahat[idx] = sv;
        u16x4 b;
        b[0] = f2bf(sv[0]); b[1] = f2bf(sv[1]); b[2] = f2bf(sv[2]); b[3] = f2bf(sv[3]);
        *(u16x4*)&la[0][row * LDP + cc] = b;
      }
      __syncthreads();
      #pragma unroll
      for (int kk = 0; kk < 2; ++kk) {
        short8 af[2], bfr[4];
        #pragma unroll
        for (int m = 0; m < 2; ++m)
          af[m] = *(const short8*)&la[0][(w * 32 + m * 16 + lr) * LDP + kk * 32 + lg * 8];
        #pragma unroll
        for (int n = 0; n < 4; ++n)
          bfr[n] = *(const short8*)&M2T[(size_t)(n * 16 + lr) * N + j0 + kk * 32 + lg * 8];
        #pragma unroll
        for (int m = 0; m < 2; ++m)
          #pragma unroll
          for (int n = 0; n < 4; ++n)
            acc[m][n] = __builtin_amdgcn_mfma_f32_16x16x32_bf16(af[m], bfr[n], acc[m][n], 0, 0, 0);
      }
    }
  }

  #pragma unroll
  for (int m = 0; m < 2; ++m)
    #pragma unroll
    for (int n = 0; n < 4; ++n)
      #pragma unroll
      for (int r = 0; r < 4; ++r) {
        int gi = i0 + w * 32 + m * 16 + lg * 4 + r;
        int gc = n * 16 + lr;
        atomicAdd(&out[(size_t)gi * DOUT + gc], acc[m][n][r]);
      }
}

// ---------------- K5: LeakyReLU on out ----------------
__global__ void leaky(float* out) {
  int i = blockIdx.x * 256 + threadIdx.x;
  if (i < N * DOUT) {
    float x = out[i];
    out[i] = x >= 0.f ? x : 0.01f * x;
  }
}

extern "C" void kernel_launch(void* const* d_in, const int* in_sizes, int n_in,
                              void* d_out, int out_size, void* d_ws, size_t ws_size,
                              hipStream_t stream) {
  const float* H   = (const float*)d_in[0];
  const float* A   = (const float*)d_in[1];
  const float* bnw = (const float*)d_in[2];
  const float* bnb = (const float*)d_in[3];
  const float* Wt  = (const float*)d_in[4];
  const float* bt  = (const float*)d_in[5];
  const float* Wo  = (const float*)d_in[6];
  const float* bo  = (const float*)d_in[7];
  float* out = (float*)d_out;
  float* Ahat = out + (size_t)N * DOUT;

  char* ws = (char*)d_ws;
  float* scale  = (float*)(ws + 0);
  float* shift  = (float*)(ws + 512);
  float* rowsum = (float*)(ws + 4096);                    // 32 KB, becomes d after dfin
  unsigned short* M2T = (unsigned short*)(ws + 65536);    // 1 MB slot [64][N]
  unsigned short* Hx  = (unsigned short*)(ws + 2097152);  // 4 MB slot
  unsigned long long* Mb = (unsigned long long*)(ws + (size_t)(6u << 20));  // 8 MB bitmask
  unsigned short* Vbf = (unsigned short*)(ws + (size_t)(14u << 20));        // 134 MB slot

  const size_t need_bf16 = ((size_t)14 << 20) + (size_t)N * N * 2;
  const bool big = ws_size >= need_bf16;

  hipMemsetAsync(rowsum, 0, N * sizeof(float), stream);
  hipMemsetAsync(out, 0, (size_t)N * DOUT * sizeof(float), stream);

  maskpack<<<4096, 256, 0, stream>>>(A, Mb);
  bn_stats<<<DIN, 256, 0, stream>>>(H, bnw, bnb, scale, shift);
  proj<<<N / 8, 256, 0, stream>>>(H, scale, shift, Wt, bt, Wo, bo, Hx, M2T);
  if (big) {
    smat<1><<<dim3(64, 64), 256, 0, stream>>>(Hx, Mb, rowsum, (void*)Vbf);
    dfin<<<N / 256, 256, 0, stream>>>(rowsum);
    outmm<1><<<dim3(16, 64), 256, 0, stream>>>((const void*)Vbf, rowsum, M2T, Ahat, out);
  } else {
    smat<0><<<dim3(64, 64), 256, 0, stream>>>(Hx, Mb, rowsum, (void*)Ahat);
    dfin<<<N / 256, 256, 0, stream>>>(rowsum);
    outmm<0><<<dim3(16, 64), 256, 0, stream>>>((const void*)Ahat, rowsum, M2T, Ahat, out);
  }
  leaky<<<(N * DOUT + 255) / 256, 256, 0, stream>>>(out);
}